// Round 1
// baseline (3180.506 us; speedup 1.0000x reference)
//
#include <hip/hip_runtime.h>
#include <hip/hip_bf16.h>

// Problem constants
#define BATCH 16
#define SEQ   512
#define HID   768
#define NH    12
#define HD    64
#define NS    5

// ---------------- QKV projection: out = x @ W.T + bias, reshaped [B,H,L,D] ----------------
// GEMM: C[m,n] = sum_k x[m,k] * W[n,k], M=8192, N=768, K=768
// BM=BN=64, BK=16, 256 threads, 4x4 micro-tile per thread.
__global__ __launch_bounds__(256) void proj_kernel(
    const float* __restrict__ x,
    const float* __restrict__ Wq, const float* __restrict__ bq,
    const float* __restrict__ Wk, const float* __restrict__ bk,
    const float* __restrict__ Wv, const float* __restrict__ bv,
    float* __restrict__ outq, float* __restrict__ outk, float* __restrict__ outv)
{
    const float* W;
    const float* bias;
    float* out;
    if (blockIdx.z == 0)      { W = Wq; bias = bq; out = outq; }
    else if (blockIdx.z == 1) { W = Wk; bias = bk; out = outk; }
    else                      { W = Wv; bias = bv; out = outv; }

    __shared__ float As[16][65];
    __shared__ float Bs[16][65];

    const int tid = threadIdx.x;
    const int m0 = blockIdx.x * 64;
    const int n0 = blockIdx.y * 64;   // == h*64

    const int tm = (tid & 15) * 4;
    const int tn = (tid >> 4) * 4;

    const int lr = tid >> 2;        // 0..63 row within tile
    const int lk = (tid & 3) * 4;   // 0,4,8,12

    float acc[4][4] = {};

    for (int k0 = 0; k0 < HID; k0 += 16) {
        float4 a4 = *(const float4*)&x[(size_t)(m0 + lr) * HID + k0 + lk];
        float4 b4 = *(const float4*)&W[(size_t)(n0 + lr) * HID + k0 + lk];
        As[lk + 0][lr] = a4.x; As[lk + 1][lr] = a4.y; As[lk + 2][lr] = a4.z; As[lk + 3][lr] = a4.w;
        Bs[lk + 0][lr] = b4.x; Bs[lk + 1][lr] = b4.y; Bs[lk + 2][lr] = b4.z; Bs[lk + 3][lr] = b4.w;
        __syncthreads();
#pragma unroll
        for (int kk = 0; kk < 16; ++kk) {
            float av[4], bvv[4];
#pragma unroll
            for (int i = 0; i < 4; ++i) av[i] = As[kk][tm + i];
#pragma unroll
            for (int j = 0; j < 4; ++j) bvv[j] = Bs[kk][tn + j];
#pragma unroll
            for (int i = 0; i < 4; ++i)
#pragma unroll
                for (int j = 0; j < 4; ++j)
                    acc[i][j] += av[i] * bvv[j];
        }
        __syncthreads();
    }

    const int h = blockIdx.y;  // BN == 64 == HD, so block's n-range is exactly one head
#pragma unroll
    for (int i = 0; i < 4; ++i) {
        int m = m0 + tm + i;
        int bb = m >> 9, l = m & 511;
#pragma unroll
        for (int j = 0; j < 4; ++j) {
            int d = tn + j;
            out[(((size_t)bb * NH + h) * SEQ + l) * HD + d] = acc[i][j] + bias[n0 + tn + j];
        }
    }
}

// ---------------- Fused biaffine attention ----------------
// One block per (b, h, 32-row i-tile). 512 threads.
// LDS: Q rows (8K) + 5 structural q' rows (40K) + full score tile 32x512 (64K)
//      + reusable 64x64(+1 pad) tile buffer for bili / K / V (16.25K)  => ~128.3 KB
__global__ __launch_bounds__(512) void attn_kernel(
    const float* __restrict__ q, const float* __restrict__ k, const float* __restrict__ v,
    const float* __restrict__ smask, const float* __restrict__ amask,
    const float* __restrict__ bili, const float* __restrict__ abs_bias,
    float* __restrict__ out)
{
    const int it = blockIdx.x;   // 0..15  (i tile)
    const int h  = blockIdx.y;   // 0..11
    const int b  = blockIdx.z;   // 0..15
    const int i0 = it * 32;
    const int tid = threadIdx.x;

    __shared__ float Qs[32][64];
    __shared__ float QPs[NS][32][64];
    __shared__ float S[32][512];
    __shared__ float Tile[64][65];

    const float* qbh = q + (((size_t)b * NH + h) * SEQ) * HD;
    const float* kbh = k + (((size_t)b * NH + h) * SEQ) * HD;
    const float* vbh = v + (((size_t)b * NH + h) * SEQ) * HD;

    // load Q rows i0..i0+31
    for (int t = tid; t < 32 * 64; t += 512) {
        int r = t >> 6, d = t & 63;
        Qs[r][d] = qbh[(size_t)(i0 + r) * HD + d];
    }
    float ab[NS];
#pragma unroll
    for (int s = 0; s < NS; ++s) ab[s] = abs_bias[s * NH + h];
    __syncthreads();

    const int tj  = tid & 63;   // column within 64-wide j tile; constant lane id pattern
    const int ti0 = tid >> 6;   // 0..7 (whole wave shares one value -> LDS broadcasts)

    // compute q' = Q @ bili[s,h]  (QP[s][i][qdim] = sum_p Q[i][p] * bili[p][qdim])
    for (int s = 0; s < NS; ++s) {
        const float* bm = bili + ((size_t)(s * NH + h)) * HD * HD;
        for (int t = tid; t < 64 * 64; t += 512) {
            Tile[t >> 6][t & 63] = bm[t];
        }
        __syncthreads();
#pragma unroll
        for (int ii = 0; ii < 4; ++ii) {
            int i = ti0 + 8 * ii;
            float acc = 0.f;
#pragma unroll
            for (int p = 0; p < 64; ++p) acc += Qs[i][p] * Tile[p][tj];
            QPs[s][i][tj] = acc;
        }
        __syncthreads();
    }

    const float scale = 0.125f;  // 1/sqrt(64)

    // scores: S[i][j] = (q.k + sum_s (q'_s.k + ab_s)*mask_s) * scale + amask[b,j]
    for (int jt = 0; jt < 8; ++jt) {
        const int j0 = jt * 64;
        for (int t = tid; t < 64 * 64; t += 512) {
            int j = t >> 6, d = t & 63;
            Tile[j][d] = kbh[(size_t)(j0 + j) * HD + d];
        }
        __syncthreads();
#pragma unroll
        for (int ii = 0; ii < 4; ++ii) {
            int i = ti0 + 8 * ii;
            float acc = 0.f;
#pragma unroll
            for (int d = 0; d < 64; ++d) acc += Qs[i][d] * Tile[tj][d];
            for (int s = 0; s < NS; ++s) {
                float bsum = 0.f;
#pragma unroll
                for (int d = 0; d < 64; ++d) bsum += QPs[s][i][d] * Tile[tj][d];
                float m = smask[(((size_t)s * BATCH + b) * SEQ + (i0 + i)) * SEQ + (j0 + tj)];
                acc += (bsum + ab[s]) * m;
            }
            S[i][j0 + tj] = acc * scale + amask[b * SEQ + j0 + tj];
        }
        __syncthreads();
    }

    // softmax over each row (16 lanes per row)
    {
        int r = tid >> 4;    // 0..31
        int l = tid & 15;
        float mx = -1e30f;
        for (int t = l; t < 512; t += 16) mx = fmaxf(mx, S[r][t]);
#pragma unroll
        for (int o = 8; o > 0; o >>= 1) mx = fmaxf(mx, __shfl_xor(mx, o, 16));
        float sum = 0.f;
        for (int t = l; t < 512; t += 16) {
            float e = __expf(S[r][t] - mx);
            S[r][t] = e;
            sum += e;
        }
#pragma unroll
        for (int o = 8; o > 0; o >>= 1) sum += __shfl_xor(sum, o, 16);
        float inv = 1.f / sum;
        for (int t = l; t < 512; t += 16) S[r][t] *= inv;
    }
    __syncthreads();

    // PV: ctx[i][d] = sum_j P[i][j] * V[j][d]
    float ctx[4] = {0.f, 0.f, 0.f, 0.f};
    for (int jt = 0; jt < 8; ++jt) {
        const int j0 = jt * 64;
        for (int t = tid; t < 64 * 64; t += 512) {
            int j = t >> 6, d = t & 63;
            Tile[j][d] = vbh[(size_t)(j0 + j) * HD + d];
        }
        __syncthreads();
#pragma unroll
        for (int ii = 0; ii < 4; ++ii) {
            int i = ti0 + 8 * ii;
            float acc = 0.f;
#pragma unroll
            for (int j = 0; j < 64; ++j) acc += S[i][j0 + j] * Tile[j][tj];
            ctx[ii] += acc;
        }
        __syncthreads();
    }

    // write out[b, l, h*64 + d]
#pragma unroll
    for (int ii = 0; ii < 4; ++ii) {
        int i = ti0 + 8 * ii;
        out[((size_t)(b * SEQ + i0 + i)) * HID + h * HD + tj] = ctx[ii];
    }
}

extern "C" void kernel_launch(void* const* d_in, const int* in_sizes, int n_in,
                              void* d_out, int out_size, void* d_ws, size_t ws_size,
                              hipStream_t stream) {
    const float* hidden   = (const float*)d_in[0];
    const float* amask    = (const float*)d_in[1];
    const float* smask    = (const float*)d_in[2];
    const float* Wq       = (const float*)d_in[3];
    const float* bq       = (const float*)d_in[4];
    const float* Wk       = (const float*)d_in[5];
    const float* bk       = (const float*)d_in[6];
    const float* Wv       = (const float*)d_in[7];
    const float* bv       = (const float*)d_in[8];
    const float* bili     = (const float*)d_in[9];
    const float* abs_bias = (const float*)d_in[10];
    float* out = (float*)d_out;

    const size_t per = (size_t)BATCH * NH * SEQ * HD;  // 6,291,456 floats
    float* q = (float*)d_ws;
    float* k = q + per;
    float* v = k + per;

    proj_kernel<<<dim3(BATCH * SEQ / 64, NH, 3), 256, 0, stream>>>(
        hidden, Wq, bq, Wk, bk, Wv, bv, q, k, v);
    attn_kernel<<<dim3(SEQ / 32, NH, BATCH), 512, 0, stream>>>(
        q, k, v, smask, amask, bili, abs_bias, out);
}

// Round 2
// 355.397 us; speedup vs baseline: 8.9492x; 8.9492x over previous
//
#include <hip/hip_runtime.h>
#include <hip/hip_bf16.h>

#define BATCH 16
#define SEQ   512
#define HID   768
#define NH    12
#define HD    64
#define NS    5

typedef __attribute__((ext_vector_type(8))) short short8;
typedef __attribute__((ext_vector_type(4))) float floatx4;

#define MFMA16(a, b, c) __builtin_amdgcn_mfma_f32_16x16x32_bf16((a), (b), (c), 0, 0, 0)

static __device__ __forceinline__ short f2bs(float f) {
    // fp32 -> bf16 RNE (finite inputs)
    unsigned x = __builtin_bit_cast(unsigned, f);
    unsigned r = (x + 0x7fffu + ((x >> 16) & 1u)) >> 16;
    return (short)r;
}

// ---------- prep: fp32 -> bf16 elementwise (n8 = n/8 groups of 8) ----------
__global__ void cvt_kernel(const float* __restrict__ src, short* __restrict__ dst, int n8) {
    int i = blockIdx.x * 256 + threadIdx.x;
    if (i >= n8) return;
    float4 a = ((const float4*)src)[2 * i];
    float4 b = ((const float4*)src)[2 * i + 1];
    short8 o;
    o[0] = f2bs(a.x); o[1] = f2bs(a.y); o[2] = f2bs(a.z); o[3] = f2bs(a.w);
    o[4] = f2bs(b.x); o[5] = f2bs(b.y); o[6] = f2bs(b.z); o[7] = f2bs(b.w);
    ((short8*)dst)[i] = o;
}

// ---------- prep: bili [s,h,p,q] -> bili^T bf16 [s,h,q,p] ----------
__global__ void bilit_kernel(const float* __restrict__ bili, short* __restrict__ bt) {
    int sh = blockIdx.x;  // 0..59
    const float* src = bili + (size_t)sh * 4096;
    short* dst = bt + (size_t)sh * 4096;
    for (int t = threadIdx.x; t < 4096; t += 256) {
        int p = t >> 6, qq = t & 63;
        dst[qq * 64 + p] = f2bs(src[p * 64 + qq]);
    }
}

// ---------- prep: pack 5 structure masks into bitfield byte [b,i,j] ----------
__global__ void pack_mask_kernel(const float* __restrict__ smask, unsigned char* __restrict__ mp) {
    int idx = blockIdx.x * 256 + threadIdx.x;  // over B*L*L = 4194304
    const size_t BLL = (size_t)BATCH * SEQ * SEQ;
    unsigned m = 0;
#pragma unroll
    for (int s = 0; s < NS; ++s)
        m |= (smask[(size_t)s * BLL + idx] != 0.f) ? (1u << s) : 0u;
    mp[idx] = (unsigned char)m;
}

// ---------- QKV projection, bf16 MFMA ----------
// C[m,n] = sum_k x[m,k] * W[n,k]; M = B*L = 8192, K = 768, per-block 64 rows x 64 cols (one head of one mat).
// q,k -> [B,H,L,D] bf16 ; v -> transposed [B,H,D,L] bf16 (B-operand layout for PV MFMA).
__global__ __launch_bounds__(256) void proj_mfma(
    const short* __restrict__ xb, const short* __restrict__ Wb,
    const float* __restrict__ bq, const float* __restrict__ bk, const float* __restrict__ bv,
    short* __restrict__ qo, short* __restrict__ ko, short* __restrict__ vto)
{
    __shared__ short As[64 * 40];  // stride 40 (80 B, 16B-aligned rows, 2-way banks = free)
    __shared__ short Bs[64 * 40];

    const int tid = threadIdx.x;
    const int m0 = blockIdx.x * 64;
    const int mh = blockIdx.y;           // 0..35
    const int mat = mh / NH, h = mh % NH;
    const short* Wm = Wb + (size_t)mat * HID * HID + (size_t)h * 64 * HID;
    const float* bias = (mat == 0) ? bq : (mat == 1) ? bk : bv;

    const int lane = tid & 63, w = tid >> 6;
    const int q4 = lane >> 4, c15 = lane & 15;
    const int srow = tid >> 2, skq = (tid & 3) * 8;

    floatx4 acc[4] = {{0.f,0.f,0.f,0.f},{0.f,0.f,0.f,0.f},{0.f,0.f,0.f,0.f},{0.f,0.f,0.f,0.f}};

    for (int k0 = 0; k0 < HID; k0 += 32) {
        *(short8*)&As[srow * 40 + skq] = *(const short8*)&xb[(size_t)(m0 + srow) * HID + k0 + skq];
        *(short8*)&Bs[srow * 40 + skq] = *(const short8*)&Wm[(size_t)srow * HID + k0 + skq];
        __syncthreads();
        short8 a = *(const short8*)&As[(w * 16 + c15) * 40 + q4 * 8];
#pragma unroll
        for (int c = 0; c < 4; ++c) {
            short8 bfr = *(const short8*)&Bs[(c * 16 + c15) * 40 + q4 * 8];
            acc[c] = MFMA16(a, bfr, acc[c]);
        }
        __syncthreads();
    }

    // epilogue: bias + store bf16
    const int mg0 = m0 + w * 16 + q4 * 4;    // row base for this lane's 4 regs (4-aligned)
    const int bb = mg0 >> 9, l0 = mg0 & 511; // same b for all 4 regs
#pragma unroll
    for (int c = 0; c < 4; ++c) {
        float bvv = bias[h * 64 + c * 16 + c15];
        if (mat < 2) {
            short* dst = (mat == 0) ? qo : ko;
#pragma unroll
            for (int r = 0; r < 4; ++r)
                dst[(((size_t)bb * NH + h) * SEQ + (l0 + r)) * HD + c * 16 + c15] = f2bs(acc[c][r] + bvv);
        } else {
            unsigned u0 = (unsigned short)f2bs(acc[c][0] + bvv) | ((unsigned)(unsigned short)f2bs(acc[c][1] + bvv) << 16);
            unsigned u1 = (unsigned short)f2bs(acc[c][2] + bvv) | ((unsigned)(unsigned short)f2bs(acc[c][3] + bvv) << 16);
            uint2 pk; pk.x = u0; pk.y = u1;
            *(uint2*)&vto[(((size_t)bb * NH + h) * HD + c * 16 + c15) * SEQ + l0] = pk;
        }
    }
}

// ---------- fused biaffine attention, bf16 MFMA flash-style ----------
// block = (64 q-rows, h, b); 256 threads (4 waves), wave w owns rows w*16..w*16+15.
__global__ __launch_bounds__(256, 3) void attn_mfma(
    const short* __restrict__ q, const short* __restrict__ k, const short* __restrict__ vt,
    const unsigned char* __restrict__ mp, const float* __restrict__ amask,
    const short* __restrict__ bilit, const float* __restrict__ abs_bias,
    float* __restrict__ out)
{
    __shared__ short Qs[64 * 72];  // stride 72 elems (144 B rows: 16B-aligned, 2-way banks = free)
    __shared__ short Ks[64 * 72];
    __shared__ short Vs[64 * 72];
    __shared__ short Ps[64 * 72];  // Qp round-trip scratch, then P tile (always wave-private rows)

    const int it = blockIdx.x, h = blockIdx.y, b = blockIdx.z;
    const int i0 = it * 64;
    const int tid = threadIdx.x, lane = tid & 63, w = tid >> 6;
    const int q4 = lane >> 4, c15 = lane & 15;

    const size_t bh = (size_t)b * NH + h;
    const short* qg = q + bh * SEQ * HD;
    const short* kg = k + bh * SEQ * HD;
    const short* vg = vt + bh * HD * SEQ;

    // stage Q tile
    for (int c = tid; c < 512; c += 256) {
        int r = c >> 3, o = (c & 7) * 8;
        *(short8*)&Qs[r * 72 + o] = *(const short8*)&qg[(size_t)(i0 + r) * HD + o];
    }
    float ab[NS];
#pragma unroll
    for (int s = 0; s < NS; ++s) ab[s] = abs_bias[s * NH + h];
    __syncthreads();

    // Q A-fragments (rows w*16 + (lane&15))
    short8 aQ0 = *(const short8*)&Qs[(w * 16 + c15) * 72 + q4 * 8];
    short8 aQ1 = *(const short8*)&Qs[(w * 16 + c15) * 72 + 32 + q4 * 8];

    // Qp_s = Q @ bili^T[s,h]   (A-frags kept in VGPRs)
    short8 aP[NS][2];
    for (int s = 0; s < NS; ++s) {
        __syncthreads();  // prior readers of Ks done
        const short* bt = bilit + ((size_t)s * NH + h) * 4096;
        for (int c = tid; c < 512; c += 256) {
            int r = c >> 3, o = (c & 7) * 8;
            *(short8*)&Ks[r * 72 + o] = *(const short8*)&bt[r * 64 + o];
        }
        __syncthreads();
#pragma unroll
        for (int ns = 0; ns < 4; ++ns) {
            short8 bf0 = *(const short8*)&Ks[(ns * 16 + c15) * 72 + q4 * 8];
            short8 bf1 = *(const short8*)&Ks[(ns * 16 + c15) * 72 + 32 + q4 * 8];
            floatx4 acc = {0.f, 0.f, 0.f, 0.f};
            acc = MFMA16(aQ0, bf0, acc);
            acc = MFMA16(aQ1, bf1, acc);
#pragma unroll
            for (int r = 0; r < 4; ++r)
                Ps[(w * 16 + q4 * 4 + r) * 72 + ns * 16 + c15] = f2bs(acc[r]);
        }
        // wave-private rows: same-wave LDS dep, no barrier needed
        aP[s][0] = *(const short8*)&Ps[(w * 16 + c15) * 72 + q4 * 8];
        aP[s][1] = *(const short8*)&Ps[(w * 16 + c15) * 72 + 32 + q4 * 8];
    }

    float m_r[4], l_r[4];
    floatx4 O[4];
#pragma unroll
    for (int r = 0; r < 4; ++r) { m_r[r] = -1e30f; l_r[r] = 0.f; }
#pragma unroll
    for (int d = 0; d < 4; ++d) O[d] = (floatx4){0.f, 0.f, 0.f, 0.f};

    const size_t mbase = (size_t)b * SEQ * SEQ;
    const int ibase = i0 + w * 16 + q4 * 4;

    for (int jt = 0; jt < 8; ++jt) {
        const int j0 = jt * 64;
        __syncthreads();  // prior K/V readers done
        for (int c = tid; c < 512; c += 256) {
            int r = c >> 3, o = (c & 7) * 8;
            *(short8*)&Ks[r * 72 + o] = *(const short8*)&kg[(size_t)(j0 + r) * HD + o];
            *(short8*)&Vs[r * 72 + o] = *(const short8*)&vg[(size_t)r * SEQ + j0 + o];
        }
        __syncthreads();

        float sv[4][4];
#pragma unroll
        for (int js = 0; js < 4; ++js) {
            const int jg = j0 + js * 16 + c15;
            unsigned mb[4];
#pragma unroll
            for (int r = 0; r < 4; ++r)
                mb[r] = mp[mbase + (size_t)(ibase + r) * SEQ + jg];
            float am = amask[b * SEQ + jg];

            short8 bf0 = *(const short8*)&Ks[(js * 16 + c15) * 72 + q4 * 8];
            short8 bf1 = *(const short8*)&Ks[(js * 16 + c15) * 72 + 32 + q4 * 8];
            floatx4 a0 = {0.f, 0.f, 0.f, 0.f};
            a0 = MFMA16(aQ0, bf0, a0);
            a0 = MFMA16(aQ1, bf1, a0);
            floatx4 as_[NS];
#pragma unroll
            for (int s = 0; s < NS; ++s) {
                floatx4 t = {0.f, 0.f, 0.f, 0.f};
                t = MFMA16(aP[s][0], bf0, t);
                t = MFMA16(aP[s][1], bf1, t);
                as_[s] = t;
            }
#pragma unroll
            for (int r = 0; r < 4; ++r) {
                float sc = a0[r];
#pragma unroll
                for (int s = 0; s < NS; ++s) {
                    float bit = (float)((mb[r] >> s) & 1u);
                    sc += bit * (as_[s][r] + ab[s]);
                }
                sv[js][r] = sc * 0.125f + am;
            }
        }

        // online softmax (row r lives in reg r of quad q4; cols spread over 16 lanes)
#pragma unroll
        for (int r = 0; r < 4; ++r) {
            float mx = fmaxf(fmaxf(sv[0][r], sv[1][r]), fmaxf(sv[2][r], sv[3][r]));
            mx = fmaxf(mx, __shfl_xor(mx, 1));
            mx = fmaxf(mx, __shfl_xor(mx, 2));
            mx = fmaxf(mx, __shfl_xor(mx, 4));
            mx = fmaxf(mx, __shfl_xor(mx, 8));
            float mn = fmaxf(m_r[r], mx);
            float alpha = __expf(m_r[r] - mn);
            m_r[r] = mn;
            float rs = 0.f;
#pragma unroll
            for (int js = 0; js < 4; ++js) {
                float p = __expf(sv[js][r] - mn);
                sv[js][r] = p;
                rs += p;
            }
            rs += __shfl_xor(rs, 1);
            rs += __shfl_xor(rs, 2);
            rs += __shfl_xor(rs, 4);
            rs += __shfl_xor(rs, 8);
            l_r[r] = l_r[r] * alpha + rs;
#pragma unroll
            for (int d = 0; d < 4; ++d) O[d][r] *= alpha;
        }

        // P -> LDS (bf16, wave-private rows), then PV
#pragma unroll
        for (int js = 0; js < 4; ++js)
#pragma unroll
            for (int r = 0; r < 4; ++r)
                Ps[(w * 16 + q4 * 4 + r) * 72 + js * 16 + c15] = f2bs(sv[js][r]);

        short8 pA0 = *(const short8*)&Ps[(w * 16 + c15) * 72 + q4 * 8];
        short8 pA1 = *(const short8*)&Ps[(w * 16 + c15) * 72 + 32 + q4 * 8];
#pragma unroll
        for (int d = 0; d < 4; ++d) {
            short8 vb0 = *(const short8*)&Vs[(d * 16 + c15) * 72 + q4 * 8];
            short8 vb1 = *(const short8*)&Vs[(d * 16 + c15) * 72 + 32 + q4 * 8];
            O[d] = MFMA16(pA0, vb0, O[d]);
            O[d] = MFMA16(pA1, vb1, O[d]);
        }
    }

    // epilogue: normalize + store fp32 out[b, l, h*64+d]
#pragma unroll
    for (int r = 0; r < 4; ++r) {
        float inv = 1.f / l_r[r];
        int i = ibase + r;
        float* orow = out + ((size_t)b * SEQ + i) * HID + h * HD;
#pragma unroll
        for (int d = 0; d < 4; ++d)
            orow[d * 16 + c15] = O[d][r] * inv;
    }
}

extern "C" void kernel_launch(void* const* d_in, const int* in_sizes, int n_in,
                              void* d_out, int out_size, void* d_ws, size_t ws_size,
                              hipStream_t stream) {
    const float* hidden   = (const float*)d_in[0];
    const float* amask    = (const float*)d_in[1];
    const float* smask    = (const float*)d_in[2];
    const float* Wq       = (const float*)d_in[3];
    const float* bq       = (const float*)d_in[4];
    const float* Wk       = (const float*)d_in[5];
    const float* bk       = (const float*)d_in[6];
    const float* Wv       = (const float*)d_in[7];
    const float* bv       = (const float*)d_in[8];
    const float* bili     = (const float*)d_in[9];
    const float* abs_bias = (const float*)d_in[10];
    float* out = (float*)d_out;

    char* ws = (char*)d_ws;
    const size_t QKV = (size_t)BATCH * NH * SEQ * HD * 2;   // 12.58 MB each (bf16)
    short* qb   = (short*)(ws);
    short* kb   = (short*)(ws + QKV);
    short* vtb  = (short*)(ws + 2 * QKV);
    short* xb   = (short*)(ws + 3 * QKV);                   // 12.58 MB
    short* Wb   = (short*)(ws + 4 * QKV);                   // 3.54 MB
    short* bltb = (short*)(ws + 4 * QKV + (size_t)3 * HID * HID * 2);
    unsigned char* mpk = (unsigned char*)(ws + 4 * QKV + (size_t)3 * HID * HID * 2
                                          + (size_t)NS * NH * HD * HD * 2);

    // prep
    cvt_kernel<<<(BATCH * SEQ * HID / 8 + 255) / 256, 256, 0, stream>>>(hidden, xb, BATCH * SEQ * HID / 8);
    cvt_kernel<<<(HID * HID / 8 + 255) / 256, 256, 0, stream>>>(Wq, Wb, HID * HID / 8);
    cvt_kernel<<<(HID * HID / 8 + 255) / 256, 256, 0, stream>>>(Wk, Wb + (size_t)HID * HID, HID * HID / 8);
    cvt_kernel<<<(HID * HID / 8 + 255) / 256, 256, 0, stream>>>(Wv, Wb + (size_t)2 * HID * HID, HID * HID / 8);
    bilit_kernel<<<NS * NH, 256, 0, stream>>>(bili, bltb);
    pack_mask_kernel<<<BATCH * SEQ * SEQ / 256, 256, 0, stream>>>(smask, mpk);

    // projection
    proj_mfma<<<dim3(BATCH * SEQ / 64, 3 * NH), 256, 0, stream>>>(xb, Wb, bq, bk, bv, qb, kb, vtb);

    // attention
    attn_mfma<<<dim3(SEQ / 64, NH, BATCH), 256, 0, stream>>>(qb, kb, vtb, mpk, amask, bltb, abs_bias, out);
}

// Round 3
// 353.675 us; speedup vs baseline: 8.9927x; 1.0049x over previous
//
#include <hip/hip_runtime.h>
#include <hip/hip_bf16.h>

#define BATCH 16
#define SEQ   512
#define HID   768
#define NH    12
#define HD    64
#define NS    5

typedef __attribute__((ext_vector_type(8))) short short8;
typedef __attribute__((ext_vector_type(4))) float floatx4;

#define MFMA16(a, b, c) __builtin_amdgcn_mfma_f32_16x16x32_bf16((a), (b), (c), 0, 0, 0)

// async global->LDS, 16B per lane, dest = ldsbase + lane*16
#define GLOAD16(gp, lp) __builtin_amdgcn_global_load_lds( \
    (const __attribute__((address_space(1))) unsigned*)(gp), \
    (__attribute__((address_space(3))) unsigned*)(lp), 16, 0, 0)

static __device__ __forceinline__ short f2bs(float f) {
    // fp32 -> bf16 RNE (finite inputs)
    unsigned x = __builtin_bit_cast(unsigned, f);
    return (short)((x + 0x7fffu + ((x >> 16) & 1u)) >> 16);
}

// ---------- prep: fp32 -> bf16 elementwise (n8 groups of 8) ----------
__global__ void cvt_kernel(const float* __restrict__ src, short* __restrict__ dst, int n8) {
    int i = blockIdx.x * 256 + threadIdx.x;
    if (i >= n8) return;
    float4 a = ((const float4*)src)[2 * i];
    float4 b = ((const float4*)src)[2 * i + 1];
    short8 o;
    o[0] = f2bs(a.x); o[1] = f2bs(a.y); o[2] = f2bs(a.z); o[3] = f2bs(a.w);
    o[4] = f2bs(b.x); o[5] = f2bs(b.y); o[6] = f2bs(b.z); o[7] = f2bs(b.w);
    ((short8*)dst)[i] = o;
}

// ---------- prep: Wq/Wk/Wv fp32 -> stacked bf16 [3*768, 768] ----------
__global__ void cvtW_kernel(const float* __restrict__ wq, const float* __restrict__ wk,
                            const float* __restrict__ wv, short* __restrict__ dst) {
    const float* src = (blockIdx.y == 0) ? wq : (blockIdx.y == 1) ? wk : wv;
    int i = blockIdx.x * 256 + threadIdx.x;  // over HID*HID/8
    if (i >= HID * HID / 8) return;
    float4 a = ((const float4*)src)[2 * i];
    float4 b = ((const float4*)src)[2 * i + 1];
    short8 o;
    o[0] = f2bs(a.x); o[1] = f2bs(a.y); o[2] = f2bs(a.z); o[3] = f2bs(a.w);
    o[4] = f2bs(b.x); o[5] = f2bs(b.y); o[6] = f2bs(b.z); o[7] = f2bs(b.w);
    ((short8*)(dst + (size_t)blockIdx.y * HID * HID))[i] = o;
}

// ---------- prep: bili [s,h,p,q] -> bili^T bf16 [s,h,q,p] ----------
__global__ void bilit_kernel(const float* __restrict__ bili, short* __restrict__ bt) {
    int sh = blockIdx.x;  // 0..59
    const float* src = bili + (size_t)sh * 4096;
    short* dst = bt + (size_t)sh * 4096;
    for (int t = threadIdx.x; t < 4096; t += 256) {
        int p = t >> 6, qq = t & 63;
        dst[qq * 64 + p] = f2bs(src[p * 64 + qq]);
    }
}

// ---------- prep: pack 5 structure masks into bitfield bytes, 4/thread ----------
__global__ void pack_mask_kernel(const float* __restrict__ smask, uchar4* __restrict__ mp) {
    int i = blockIdx.x * 256 + threadIdx.x;  // over B*L*L/4 = 1048576
    const size_t BLL4 = (size_t)BATCH * SEQ * SEQ / 4;
    const float4* f = (const float4*)smask;
    unsigned b0 = 0, b1 = 0, b2 = 0, b3 = 0;
#pragma unroll
    for (int s = 0; s < NS; ++s) {
        float4 v = f[(size_t)s * BLL4 + i];
        b0 |= (v.x != 0.f) ? (1u << s) : 0u;
        b1 |= (v.y != 0.f) ? (1u << s) : 0u;
        b2 |= (v.z != 0.f) ? (1u << s) : 0u;
        b3 |= (v.w != 0.f) ? (1u << s) : 0u;
    }
    mp[i] = make_uchar4((unsigned char)b0, (unsigned char)b1, (unsigned char)b2, (unsigned char)b3);
}

// ---------- QKV projection, m97-style 128x128 tile + global_load_lds ----------
// C[m,n] = sum_k x[m,k]*W[n,k]; M=8192, N=2304 (3 mats stacked), K=768.
// q (pre-scaled by 0.125), k -> [B,H,L,D] bf16; v -> [B,H,D,L] bf16.
__global__ __launch_bounds__(256) void proj_mfma(
    const short* __restrict__ xb, const short* __restrict__ Wb,
    const float* __restrict__ bq, const float* __restrict__ bk, const float* __restrict__ bv,
    short* __restrict__ qo, short* __restrict__ ko, short* __restrict__ vto)
{
    __shared__ short As[128 * 32];  // row-major, stride 32 elems (64 B) — no pad (global_load_lds)
    __shared__ short Bs[128 * 32];

    const int tid = threadIdx.x, lane = tid & 63, w = tid >> 6;
    const int q4 = lane >> 4, c15 = lane & 15;
    const int m0 = blockIdx.x * 128, n0 = blockIdx.y * 128;
    const int wrow = (w & 1) * 64, wcol = (w >> 1) * 64;

    // staging: wave w covers rows [w*32, w*32+32) via 2 instrs per matrix
    const int srow = lane >> 2;        // 0..15 within 16-row chunk
    const int scol = (lane & 3) * 8;   // element col within 32
    const short* gA = xb + (size_t)(m0 + w * 32 + srow) * HID + scol;
    const short* gB = Wb + (size_t)(n0 + w * 32 + srow) * HID + scol;
    short* lA = As + w * 1024;  // elems; = w*2048 B
    short* lB = Bs + w * 1024;

    floatx4 acc[4][4];
#pragma unroll
    for (int i = 0; i < 4; ++i)
#pragma unroll
        for (int j = 0; j < 4; ++j) acc[i][j] = (floatx4){0.f, 0.f, 0.f, 0.f};

    for (int k0 = 0; k0 < HID; k0 += 32) {
        __syncthreads();  // prior frag reads done
        GLOAD16(gA + k0,             lA);
        GLOAD16(gA + k0 + 16 * HID,  lA + 512);
        GLOAD16(gB + k0,             lB);
        GLOAD16(gB + k0 + 16 * HID,  lB + 512);
        __syncthreads();  // drains vmcnt

        short8 af[4], bf[4];
#pragma unroll
        for (int ri = 0; ri < 4; ++ri)
            af[ri] = *(const short8*)&As[(wrow + ri * 16 + c15) * 32 + q4 * 8];
#pragma unroll
        for (int ci = 0; ci < 4; ++ci)
            bf[ci] = *(const short8*)&Bs[(wcol + ci * 16 + c15) * 32 + q4 * 8];
#pragma unroll
        for (int ri = 0; ri < 4; ++ri)
#pragma unroll
            for (int ci = 0; ci < 4; ++ci)
                acc[ri][ci] = MFMA16(af[ri], bf[ci], acc[ri][ci]);
    }

    const int matq = n0 / HID;  // block-uniform: 0,1,2
    const float* bias = (matq == 0) ? bq : (matq == 1) ? bk : bv;

#pragma unroll
    for (int ci = 0; ci < 4; ++ci) {
        const int nm = (n0 - matq * HID) + wcol + ci * 16 + c15;  // 0..767
        const int h = nm >> 6, d = nm & 63;
        const float bvv = bias[nm];
#pragma unroll
        for (int ri = 0; ri < 4; ++ri) {
            const int mg0 = m0 + wrow + ri * 16 + q4 * 4;  // 4-aligned row base
            const int bb = mg0 >> 9, l0 = mg0 & 511;
            if (matq == 0) {
#pragma unroll
                for (int r = 0; r < 4; ++r)
                    qo[(((size_t)bb * NH + h) * SEQ + (l0 + r)) * HD + d] =
                        f2bs((acc[ri][ci][r] + bvv) * 0.125f);  // fold 1/sqrt(64), exact pow2
            } else if (matq == 1) {
#pragma unroll
                for (int r = 0; r < 4; ++r)
                    ko[(((size_t)bb * NH + h) * SEQ + (l0 + r)) * HD + d] =
                        f2bs(acc[ri][ci][r] + bvv);
            } else {
                unsigned u0 = (unsigned short)f2bs(acc[ri][ci][0] + bvv) |
                              ((unsigned)(unsigned short)f2bs(acc[ri][ci][1] + bvv) << 16);
                unsigned u1 = (unsigned short)f2bs(acc[ri][ci][2] + bvv) |
                              ((unsigned)(unsigned short)f2bs(acc[ri][ci][3] + bvv) << 16);
                uint2 pk; pk.x = u0; pk.y = u1;
                *(uint2*)&vto[(((size_t)bb * NH + h) * HD + d) * SEQ + l0] = pk;
            }
        }
    }
}

// ---------- fused biaffine attention, 128-wide j-tiles ----------
// block = (64 q-rows, h, b); 256 threads (4 waves), wave w owns rows w*16..w*16+15.
// q arrives pre-scaled by 0.125; abt table carries 0.125*sum(bits*abs_bias).
__global__ __launch_bounds__(256) void attn_mfma(
    const short* __restrict__ q, const short* __restrict__ k, const short* __restrict__ vt,
    const unsigned char* __restrict__ mp, const float* __restrict__ amask,
    const short* __restrict__ bilit, const float* __restrict__ abs_bias,
    float* __restrict__ out)
{
    __shared__ short U0[64 * 136];  // Qs (stride 72) in prologue, then P tile (stride 136)
    __shared__ short Ks[128 * 72];  // K rows (and bili staging in prologue)
    __shared__ short Vs[64 * 136];  // V^T: [d][j], stride 136
    __shared__ float abt[32];       // 0.125 * sum_{s in bits} abs_bias[s,h]

    const int it = blockIdx.x, h = blockIdx.y, b = blockIdx.z;
    const int i0 = it * 64;
    const int tid = threadIdx.x, lane = tid & 63, w = tid >> 6;
    const int q4 = lane >> 4, c15 = lane & 15;

    const size_t bh = (size_t)b * NH + h;
    const short* qg = q + bh * SEQ * HD;
    const short* kg = k + bh * SEQ * HD;
    const short* vg = vt + bh * HD * SEQ;

    if (tid < 32) {
        float a = 0.f;
#pragma unroll
        for (int s = 0; s < NS; ++s)
            if (tid & (1u << s)) a += abs_bias[s * NH + h];
        abt[tid] = a * 0.125f;
    }

    // stage Q (stride 72)
    for (int c = tid; c < 512; c += 256) {
        int r = c >> 3, o = (c & 7) * 8;
        *(short8*)&U0[r * 72 + o] = *(const short8*)&qg[(size_t)(i0 + r) * HD + o];
    }
    __syncthreads();
    short8 aQ0 = *(const short8*)&U0[(w * 16 + c15) * 72 + q4 * 8];
    short8 aQ1 = *(const short8*)&U0[(w * 16 + c15) * 72 + 32 + q4 * 8];

    // Qp_s = Q @ bili^T[s,h]; A-frags kept in VGPRs (LDS roundtrip is wave-private)
    short8 aP[NS][2];
    for (int s = 0; s < NS; ++s) {
        __syncthreads();  // aQ loads done (s=0) / prior readers done
        const short* bt = bilit + ((size_t)s * NH + h) * 4096;
        for (int c = tid; c < 512; c += 256) {
            int r = c >> 3, o = (c & 7) * 8;
            *(short8*)&Ks[r * 72 + o] = *(const short8*)&bt[r * 64 + o];
        }
        __syncthreads();
#pragma unroll
        for (int ns = 0; ns < 4; ++ns) {
            short8 bf0 = *(const short8*)&Ks[(ns * 16 + c15) * 72 + q4 * 8];
            short8 bf1 = *(const short8*)&Ks[(ns * 16 + c15) * 72 + 32 + q4 * 8];
            floatx4 acc = {0.f, 0.f, 0.f, 0.f};
            acc = MFMA16(aQ0, bf0, acc);
            acc = MFMA16(aQ1, bf1, acc);
#pragma unroll
            for (int r = 0; r < 4; ++r)
                U0[(w * 16 + q4 * 4 + r) * 136 + ns * 16 + c15] = f2bs(acc[r]);
        }
        aP[s][0] = *(const short8*)&U0[(w * 16 + c15) * 136 + q4 * 8];
        aP[s][1] = *(const short8*)&U0[(w * 16 + c15) * 136 + 32 + q4 * 8];
    }

    float m_r[4], l_r[4];
    floatx4 O[4];
#pragma unroll
    for (int r = 0; r < 4; ++r) { m_r[r] = -1e30f; l_r[r] = 0.f; }
#pragma unroll
    for (int d = 0; d < 4; ++d) O[d] = (floatx4){0.f, 0.f, 0.f, 0.f};

    const int ibase = i0 + w * 16 + q4 * 4;
    const unsigned char* rowp[4];
#pragma unroll
    for (int r = 0; r < 4; ++r)
        rowp[r] = mp + (size_t)b * SEQ * SEQ + (size_t)(ibase + r) * SEQ + c15;
    const float* amrow = amask + b * SEQ;

    for (int jt = 0; jt < 4; ++jt) {
        const int j0 = jt * 128;
        __syncthreads();  // prior iter K/V/P readers done
        for (int c = tid; c < 1024; c += 256) {
            int r = c >> 3, o = (c & 7) * 8;
            *(short8*)&Ks[r * 72 + o] = *(const short8*)&kg[(size_t)(j0 + r) * HD + o];
        }
        for (int c = tid; c < 1024; c += 256) {
            int d = c >> 4, o = (c & 15) * 8;
            *(short8*)&Vs[d * 136 + o] = *(const short8*)&vg[(size_t)d * SEQ + j0 + o];
        }
        __syncthreads();

        float sv[8][4];
#pragma unroll
        for (int js = 0; js < 8; ++js) {
            const short8 bf0 = *(const short8*)&Ks[(js * 16 + c15) * 72 + q4 * 8];
            const short8 bf1 = *(const short8*)&Ks[(js * 16 + c15) * 72 + 32 + q4 * 8];
            floatx4 a0 = {0.f, 0.f, 0.f, 0.f};
            a0 = MFMA16(aQ0, bf0, a0);
            a0 = MFMA16(aQ1, bf1, a0);
            floatx4 as_[NS];
#pragma unroll
            for (int s = 0; s < NS; ++s) {
                floatx4 t = {0.f, 0.f, 0.f, 0.f};
                t = MFMA16(aP[s][0], bf0, t);
                t = MFMA16(aP[s][1], bf1, t);
                as_[s] = t;
            }
            const float am = amrow[j0 + js * 16 + c15];
#pragma unroll
            for (int r = 0; r < 4; ++r) {
                unsigned mb = rowp[r][j0 + js * 16];
                float sc = a0[r] + am + abt[mb & 31];
#pragma unroll
                for (int s = 0; s < NS; ++s)
                    sc = fmaf((float)((mb >> s) & 1u), as_[s][r], sc);
                sv[js][r] = sc;
            }
        }

        // online softmax over 128 cols
#pragma unroll
        for (int r = 0; r < 4; ++r) {
            float mx = sv[0][r];
#pragma unroll
            for (int js = 1; js < 8; ++js) mx = fmaxf(mx, sv[js][r]);
            mx = fmaxf(mx, __shfl_xor(mx, 1));
            mx = fmaxf(mx, __shfl_xor(mx, 2));
            mx = fmaxf(mx, __shfl_xor(mx, 4));
            mx = fmaxf(mx, __shfl_xor(mx, 8));
            float mn = fmaxf(m_r[r], mx);
            float alpha = __expf(m_r[r] - mn);
            m_r[r] = mn;
            float rs = 0.f;
#pragma unroll
            for (int js = 0; js < 8; ++js) {
                float p = __expf(sv[js][r] - mn);
                sv[js][r] = p;
                rs += p;
            }
            rs += __shfl_xor(rs, 1);
            rs += __shfl_xor(rs, 2);
            rs += __shfl_xor(rs, 4);
            rs += __shfl_xor(rs, 8);
            l_r[r] = l_r[r] * alpha + rs;
#pragma unroll
            for (int d = 0; d < 4; ++d) O[d][r] *= alpha;
        }

        // P -> LDS bf16 (wave-private rows), then PV
#pragma unroll
        for (int js = 0; js < 8; ++js)
#pragma unroll
            for (int r = 0; r < 4; ++r)
                U0[(w * 16 + q4 * 4 + r) * 136 + js * 16 + c15] = f2bs(sv[js][r]);

#pragma unroll
        for (int kk = 0; kk < 4; ++kk) {
            short8 pA = *(const short8*)&U0[(w * 16 + c15) * 136 + kk * 32 + q4 * 8];
#pragma unroll
            for (int d = 0; d < 4; ++d) {
                short8 vb = *(const short8*)&Vs[(d * 16 + c15) * 136 + kk * 32 + q4 * 8];
                O[d] = MFMA16(pA, vb, O[d]);
            }
        }
    }

    // epilogue: normalize + store fp32 out[b, l, h*64+d]
#pragma unroll
    for (int r = 0; r < 4; ++r) {
        float inv = 1.f / l_r[r];
        float* orow = out + ((size_t)b * SEQ + ibase + r) * HID + h * HD;
#pragma unroll
        for (int d = 0; d < 4; ++d)
            orow[d * 16 + c15] = O[d][r] * inv;
    }
}

extern "C" void kernel_launch(void* const* d_in, const int* in_sizes, int n_in,
                              void* d_out, int out_size, void* d_ws, size_t ws_size,
                              hipStream_t stream) {
    const float* hidden   = (const float*)d_in[0];
    const float* amask    = (const float*)d_in[1];
    const float* smask    = (const float*)d_in[2];
    const float* Wq       = (const float*)d_in[3];
    const float* bq       = (const float*)d_in[4];
    const float* Wk       = (const float*)d_in[5];
    const float* bk       = (const float*)d_in[6];
    const float* Wv       = (const float*)d_in[7];
    const float* bv       = (const float*)d_in[8];
    const float* bili     = (const float*)d_in[9];
    const float* abs_bias = (const float*)d_in[10];
    float* out = (float*)d_out;

    char* ws = (char*)d_ws;
    const size_t QKV = (size_t)BATCH * NH * SEQ * HD * 2;   // 12.58 MB each (bf16)
    short* qb   = (short*)(ws);
    short* kb   = (short*)(ws + QKV);
    short* vtb  = (short*)(ws + 2 * QKV);
    short* xb   = (short*)(ws + 3 * QKV);                   // 12.58 MB
    short* Wb   = (short*)(ws + 4 * QKV);                   // 3.54 MB (3 mats stacked)
    short* bltb = (short*)(ws + 4 * QKV + (size_t)3 * HID * HID * 2);
    unsigned char* mpk = (unsigned char*)(ws + 4 * QKV + (size_t)3 * HID * HID * 2
                                          + (size_t)NS * NH * HD * HD * 2);

    // prep
    cvt_kernel<<<(BATCH * SEQ * HID / 8 + 255) / 256, 256, 0, stream>>>(hidden, xb, BATCH * SEQ * HID / 8);
    cvtW_kernel<<<dim3((HID * HID / 8 + 255) / 256, 3), 256, 0, stream>>>(Wq, Wk, Wv, Wb);
    bilit_kernel<<<NS * NH, 256, 0, stream>>>(bili, bltb);
    pack_mask_kernel<<<BATCH * SEQ * SEQ / 4 / 256, 256, 0, stream>>>(smask, (uchar4*)mpk);

    // projection: 128x128 tiles over [8192 x 2304]
    proj_mfma<<<dim3(BATCH * SEQ / 128, 3 * HID / 128), 256, 0, stream>>>(
        xb, Wb, bq, bk, bv, qb, kb, vtb);

    // attention
    attn_mfma<<<dim3(SEQ / 64, NH, BATCH), 256, 0, stream>>>(
        qb, kb, vtb, mpk, amask, bltb, abs_bias, out);
}